// Round 4
// baseline (281.018 us; speedup 1.0000x reference)
//
#include <hip/hip_runtime.h>
#include <math.h>

#define N_USERS 1000000
#define N_ITEMS 100000
#define EMB 16
#define OUTD 16
#define NH 4
#define HID 32
#define BB 8192
#define SS 200
#define LL 50
#define NSUPP 50000

#define TT 1024                        // rows per LDS tile
#define NT ((NSUPP + TT - 1) / TT)     // 49 tiles
#define GB 128                         // b's per attn block

typedef float v4f __attribute__((ext_vector_type(4)));
typedef float v8f __attribute__((ext_vector_type(8)));
typedef _Float16 h2 __attribute__((ext_vector_type(2)));
typedef _Float16 h4 __attribute__((ext_vector_type(4)));
typedef _Float16 h8 __attribute__((ext_vector_type(8)));

// ---------------------------------------------------------------------------
// Kernel 1 (fused prep): blocks [0, NSUPP/16) compute Ksupp (fp16);
// blocks [NSUPP/16, NSUPP/16 + BB/4) compute user_init -> qbuf.
// ---------------------------------------------------------------------------
__global__ __launch_bounds__(256) void prep_kernel(
    const float* __restrict__ user_emb,
    const int*   __restrict__ supp_users,
    const float* __restrict__ wk,
    _Float16*    __restrict__ Ksupp,
    const float* __restrict__ item_emb,
    const int*   __restrict__ history,
    const int*   __restrict__ history_len,
    const float* __restrict__ wq,
    float*       __restrict__ qbuf)
{
    __shared__ float s_wk[NH * EMB * OUTD];   // branch 1
    __shared__ float s_u[16][EMB];
    __shared__ float s_ui[4][EMB];            // branch 2
    __shared__ float s_wq[NH * EMB * OUTD];

    int t = threadIdx.x;
    if (blockIdx.x < NSUPP / 16) {
        for (int i = t; i < NH * EMB * OUTD; i += 256) s_wk[i] = wk[i];
        int n0 = blockIdx.x * 16;
        {
            int ul = t >> 4, e = t & 15;
            int row = supp_users[n0 + ul];
            s_u[ul][e] = user_emb[(size_t)row * EMB + e];
        }
        __syncthreads();
        int h   = t >> 6;
        int sub = (t >> 4) & 3;
        int o   = t & 15;
#pragma unroll
        for (int r = 0; r < 4; ++r) {
            int ul = sub + 4 * r;
            float acc = 0.f;
#pragma unroll
            for (int e = 0; e < EMB; ++e)
                acc += s_u[ul][e] * s_wk[(h * EMB + e) * OUTD + o];
            Ksupp[((size_t)h * NSUPP + n0 + ul) * OUTD + o] = (_Float16)acc;
        }
    } else {
        for (int i = t; i < NH * EMB * OUTD; i += 256) s_wq[i] = wq[i];
        int g    = t >> 6;
        int lane = t & 63;
        int l4   = lane >> 4;
        int e    = lane & 15;
        int b    = (blockIdx.x - NSUPP / 16) * 4 + g;

        float sum = 0.f;
        for (int l = l4; l < LL; l += 4) {
            int it = __builtin_nontemporal_load(history + (size_t)b * LL + l);
            sum += item_emb[(size_t)it * EMB + e];
        }
        sum += __shfl_xor(sum, 16);
        sum += __shfl_xor(sum, 32);
        if (lane < EMB) s_ui[g][lane] = sum / (float)history_len[b];
        __syncthreads();

        int h = (t >> 4) & 3;
        int o = t & 15;
        float acc = 0.f;
#pragma unroll
        for (int ee = 0; ee < EMB; ++ee)
            acc += s_ui[g][ee] * s_wq[(h * EMB + ee) * OUTD + o];
        qbuf[((size_t)b * NH + h) * OUTD + o] = acc;
    }
}

// ---------------------------------------------------------------------------
// Kernel 2: LDS-tiled attention. Block = 1 head x 128 b's (512 thr, 8 waves,
// 16 b per wave, quad per b). The head's 1.6 MB fp16 K slice is streamed
// through LDS in 49 double-buffered 32 KB tiles (reg-staged: issue loads ->
// process current tile -> ds_write -> barrier). Rounds 0-3 proved the random
// L2 gather path saturates at ~4 cy/row-request/CU (6.55 M requests = 44 us,
// invariant to bytes & instruction shape); this converts those into coalesced
// streams + LDS random reads.
// No-max softmax (|q.k|~1e-5, verified absmax 0.0) => order-free accumulation
// => samples can be consumed tile-by-tile in SORTED order. Phase 0 bitonic-
// sorts each b's 200 indices in-register (64 lanes x 4 regs, static network),
// overlapping tile-0 load latency; lists live in LDS as u16, consumed 4/iter
// per quad with ballot-counted pointer advance.
// Head->XCD pinning kept: h=(blk&7)>>1.
// ---------------------------------------------------------------------------
__global__ __launch_bounds__(512, 2) void attn_kernel(
    const _Float16* __restrict__ Ksupp,
    const float* __restrict__ qbuf,
    const int*   __restrict__ sample_index,
    const float* __restrict__ wv,
    float*       __restrict__ gat)
{
    __shared__ __align__(16) _Float16 s_tile[2][TT * OUTD];  // 2 x 32 KB
    __shared__ unsigned short s_idx[GB * 256];               // 64 KB

    int blk   = blockIdx.x;
    int h     = (blk & 7) >> 1;
    int btile = ((blk >> 3) << 1) | (blk & 1);   // 0..63
    int wave  = threadIdx.x >> 6;
    int lane  = threadIdx.x & 63;
    int tid   = threadIdx.x;
    int g     = lane >> 2;       // quad id: which b of the wave's 16
    int qt    = lane & 3;        // slot within quad

    const char* Khb = (const char*)(Ksupp + (size_t)h * NSUPP * OUTD);
    int b_base = btile * GB;

    // ---- issue tile-0 global loads (in flight during the sort phase) ----
    v4f st[4];
#pragma unroll
    for (int m = 0; m < 4; ++m)
        st[m] = *(const v4f*)(Khb + (size_t)(m * 512 + tid) * 16);

    // ---- phase 0: per-b bitonic sort of sample indices -> s_idx (u16) ----
    {
        const int* si0 = sample_index + ((size_t)h * BB + (b_base + wave * 16)) * SS;
        unsigned n0 = (unsigned)__builtin_nontemporal_load(si0 + lane);
        unsigned n1 = (unsigned)__builtin_nontemporal_load(si0 + 64 + lane);
        unsigned n2 = (unsigned)__builtin_nontemporal_load(si0 + 128 + lane);
        unsigned n3 = (lane < SS - 192) ?
            (unsigned)__builtin_nontemporal_load(si0 + 192 + lane) : 0xFFFFu;
        for (int bs = 0; bs < 16; ++bs) {
            unsigned v[4] = {n0, n1, n2, n3};
            if (bs < 15) {                      // software-pipeline next list
                const int* si = si0 + (size_t)(bs + 1) * SS;
                n0 = (unsigned)__builtin_nontemporal_load(si + lane);
                n1 = (unsigned)__builtin_nontemporal_load(si + 64 + lane);
                n2 = (unsigned)__builtin_nontemporal_load(si + 128 + lane);
                n3 = (lane < SS - 192) ?
                    (unsigned)__builtin_nontemporal_load(si + 192 + lane) : 0xFFFFu;
            }
            // bitonic sort of 256 elems: element e = r*64 + lane, all static
#pragma unroll
            for (int kk = 2; kk <= 256; kk <<= 1) {
#pragma unroll
                for (int j = kk >> 1; j > 0; j >>= 1) {
                    if (j >= 64) {
                        const int jr = j >> 6;  // 1 or 2
#pragma unroll
                        for (int r = 0; r < 4; ++r) {
                            if ((r & jr) == 0) {
                                const int rp = r | jr;
                                bool up = (((unsigned)(r * 64) & (unsigned)kk) == 0u);
                                unsigned a = v[r], bq = v[rp];
                                unsigned mn = a < bq ? a : bq;
                                unsigned mx = a < bq ? bq : a;
                                v[r]  = up ? mn : mx;
                                v[rp] = up ? mx : mn;
                            }
                        }
                    } else {
#pragma unroll
                        for (int r = 0; r < 4; ++r) {
                            unsigned a = v[r];
                            unsigned p = (unsigned)__shfl_xor((int)a, j, 64);
                            int e = r * 64 + lane;
                            bool lower = ((e & j) == 0);
                            bool up    = ((e & kk) == 0);
                            unsigned mn = a < p ? a : p;
                            unsigned mx = a < p ? p : a;
                            v[r] = (up == lower) ? mn : mx;
                        }
                    }
                }
            }
            int bl = wave * 16 + bs;
            s_idx[bl * 256 +       lane] = (unsigned short)v[0];
            s_idx[bl * 256 +  64 + lane] = (unsigned short)v[1];
            s_idx[bl * 256 + 128 + lane] = (unsigned short)v[2];
            s_idx[bl * 256 + 192 + lane] = (unsigned short)v[3];
        }
    }

    // ---- per-lane q (full row, fp16 pairs for fdot2) ----
    int b_local = wave * 16 + g;
    int bfull   = b_base + b_local;
    const v4f* qrow = (const v4f*)(qbuf + ((size_t)bfull * NH + h) * OUTD);
    h4 A = __builtin_convertvector(qrow[0], h4);
    h4 Bv = __builtin_convertvector(qrow[1], h4);
    h4 Cv = __builtin_convertvector(qrow[2], h4);
    h4 Dv = __builtin_convertvector(qrow[3], h4);
    h2 q0 = {A.x, A.y},  q1 = {A.z, A.w};
    h2 q2 = {Bv.x, Bv.y}, q3 = {Bv.z, Bv.w};
    h2 q4 = {Cv.x, Cv.y}, q5 = {Cv.z, Cv.w};
    h2 q6 = {Dv.x, Dv.y}, q7 = {Dv.z, Dv.w};

    // publish tile 0
#pragma unroll
    for (int m = 0; m < 4; ++m)
        *(v4f*)((char*)&s_tile[0][0] + (size_t)(m * 512 + tid) * 16) = st[m];
    __syncthreads();

    // ---- main loop over 49 tiles ----
    float l = 0.f;
    v8f cA = {0.f,0.f,0.f,0.f,0.f,0.f,0.f,0.f};
    v8f cB = {0.f,0.f,0.f,0.f,0.f,0.f,0.f,0.f};
    int ptr = 0;                                  // per-quad consume pointer
    const unsigned short* qlist = &s_idx[b_local * 256];

    for (int t = 0; t < NT; ++t) {
        int cur = t & 1;
        if (t + 1 < NT) {                         // issue next-tile loads
#pragma unroll
            for (int m = 0; m < 4; ++m)
                st[m] = *(const v4f*)(Khb + (size_t)(t + 1) * (TT * OUTD * 2)
                                          + (size_t)(m * 512 + tid) * 16);
        }
        int lo = t * TT;
        int hi = lo + TT; if (hi > NSUPP) hi = NSUPP;
        const h8* tile8 = (const h8*)&s_tile[cur][0];

        bool qdone = false;
        for (;;) {
            int e = (int)qlist[ptr + qt];         // <=203, in-bounds of 256
            bool valid = (!qdone) && (e < hi);    // sorted => e >= lo already
            int row = valid ? (e - lo) : 0;
            h8 k0 = tile8[row * 2];
            h8 k1 = tile8[row * 2 + 1];
            float p;
            p = __builtin_amdgcn_fdot2(__builtin_shufflevector(k0, k0, 0, 1), q0, 0.f, false);
            p = __builtin_amdgcn_fdot2(__builtin_shufflevector(k0, k0, 2, 3), q1, p, false);
            p = __builtin_amdgcn_fdot2(__builtin_shufflevector(k0, k0, 4, 5), q2, p, false);
            p = __builtin_amdgcn_fdot2(__builtin_shufflevector(k0, k0, 6, 7), q3, p, false);
            p = __builtin_amdgcn_fdot2(__builtin_shufflevector(k1, k1, 0, 1), q4, p, false);
            p = __builtin_amdgcn_fdot2(__builtin_shufflevector(k1, k1, 2, 3), q5, p, false);
            p = __builtin_amdgcn_fdot2(__builtin_shufflevector(k1, k1, 4, 5), q6, p, false);
            p = __builtin_amdgcn_fdot2(__builtin_shufflevector(k1, k1, 6, 7), q7, p, false);
            float w = valid ? __expf(p) : 0.f;    // no-max softmax
            l += w;
            cA += w * __builtin_convertvector(k0, v8f);
            cB += w * __builtin_convertvector(k1, v8f);
            unsigned long long bal = __ballot(valid);
            int hits = __popcll((bal >> (g * 4)) & 0xFull);
            ptr += hits;                          // uniform within quad
            if (hits < 4) qdone = true;
            if (__ballot(!qdone) == 0ull) break;
        }

        if (t + 1 < NT) {                         // write next tile (loads landed
#pragma unroll                                    // during processing)
            for (int m = 0; m < 4; ++m)
                *(v4f*)((char*)&s_tile[cur ^ 1][0] + (size_t)(m * 512 + tid) * 16) = st[m];
        }
        __syncthreads();
    }

    // ---- quad reduce + wv projection ----
    l += __shfl_xor(l, 1); l += __shfl_xor(l, 2);
#pragma unroll
    for (int i = 0; i < 8; ++i) {
        cA[i] += __shfl_xor(cA[i], 1); cA[i] += __shfl_xor(cA[i], 2);
        cB[i] += __shfl_xor(cB[i], 1); cB[i] += __shfl_xor(cB[i], 2);
    }
    float inv = 1.f / l;

    v4f acc = {0.f, 0.f, 0.f, 0.f};
    const float* wvh = wv + (size_t)h * OUTD * OUTD + qt * 4;   // cols qt*4..+3
#pragma unroll
    for (int j = 0; j < 8; ++j) {
        acc += cA[j] * *(const v4f*)(wvh + (size_t)j * OUTD);
        acc += cB[j] * *(const v4f*)(wvh + (size_t)(j + 8) * OUTD);
    }
    acc *= inv;
    *(v4f*)(gat + (size_t)bfull * (NH * OUTD) + h * OUTD + qt * 4) = acc;
}

// ---------------------------------------------------------------------------
// Kernel 3: epilogue per b (4 b per 256-thread block, one wave per b).
// ---------------------------------------------------------------------------
__global__ __launch_bounds__(256) void epilogue_kernel(
    const float* __restrict__ gat,
    const float* __restrict__ item_emb,
    const float* __restrict__ w_out,
    const float* __restrict__ l1_w, const float* __restrict__ l1_b,
    const float* __restrict__ l2_w, const float* __restrict__ l2_b,
    const float* __restrict__ l3_w, const float* __restrict__ l3_b,
    const float* __restrict__ user_bias, const float* __restrict__ item_bias,
    const int*   __restrict__ x,
    float*       __restrict__ out)
{
    int t    = threadIdx.x;
    int g    = t >> 6;
    int lane = t & 63;
    int b    = blockIdx.x * 4 + g;

    __shared__ float s_gat[4][NH * OUTD];
    __shared__ float s_ue[4][OUTD];
    __shared__ float s_ie[4][EMB];
    __shared__ float s_x1[4][HID];
    __shared__ float s_x2[4][HID / 2];

    int uid = x[(size_t)b * 2 + 0];
    int iid = x[(size_t)b * 2 + 1];

    s_gat[g][lane] = gat[(size_t)b * (NH * OUTD) + lane];
    if (lane < EMB) s_ie[g][lane] = item_emb[(size_t)iid * EMB + lane];
    __syncthreads();

    if (lane < OUTD) {
        float acc = 0.f;
#pragma unroll
        for (int j = 0; j < NH * OUTD; ++j) acc += s_gat[g][j] * w_out[j * OUTD + lane];
        s_ue[g][lane] = acc;
    }
    __syncthreads();

    if (lane < HID) {
        float acc = l1_b[lane];
#pragma unroll
        for (int i = 0; i < EMB; ++i) {
            float ue = s_ue[g][i], ie = s_ie[g][i];
            acc += ue * l1_w[i * HID + lane]
                 + ie * l1_w[(EMB + i) * HID + lane]
                 + ue * ie * l1_w[(2 * EMB + i) * HID + lane];
        }
        s_x1[g][lane] = tanhf(acc);
    }
    __syncthreads();

    if (lane < HID / 2) {
        float acc = l2_b[lane];
#pragma unroll
        for (int j = 0; j < HID; ++j) acc += s_x1[g][j] * l2_w[j * (HID / 2) + lane];
        s_x2[g][lane] = tanhf(acc);
    }
    __syncthreads();

    if (lane == 0) {
        float x3 = l3_b[0];
#pragma unroll
        for (int j = 0; j < HID / 2; ++j) x3 += s_x2[g][j] * l3_w[j];
        float ratings = 0.f;
#pragma unroll
        for (int o = 0; o < OUTD; ++o) ratings += s_ue[g][o] * s_ie[g][o];
        out[b] = 0.5f * (ratings + x3) + user_bias[uid] + item_bias[iid];
    }
}

// ---------------------------------------------------------------------------
extern "C" void kernel_launch(void* const* d_in, const int* in_sizes, int n_in,
                              void* d_out, int out_size, void* d_ws, size_t ws_size,
                              hipStream_t stream) {
    const float* user_embedding = (const float*)d_in[0];
    const float* item_embedding = (const float*)d_in[1];
    const float* wq             = (const float*)d_in[2];
    const float* wk             = (const float*)d_in[3];
    const float* wv             = (const float*)d_in[4];
    const float* w_out          = (const float*)d_in[5];
    const float* l1_w           = (const float*)d_in[6];
    const float* l1_b           = (const float*)d_in[7];
    const float* l2_w           = (const float*)d_in[8];
    const float* l2_b           = (const float*)d_in[9];
    const float* l3_w           = (const float*)d_in[10];
    const float* l3_b           = (const float*)d_in[11];
    const float* user_bias      = (const float*)d_in[12];
    const float* item_bias      = (const float*)d_in[13];
    const int*   x              = (const int*)d_in[14];
    const int*   history        = (const int*)d_in[15];
    const int*   history_len    = (const int*)d_in[16];
    const int*   supp_users     = (const int*)d_in[17];
    const int*   sample_index   = (const int*)d_in[18];
    float* out = (float*)d_out;

    char* ws = (char*)d_ws;
    _Float16* Ksupp = (_Float16*)ws;                              // 6.4 MB
    ws += (size_t)NH * NSUPP * OUTD * sizeof(_Float16);
    float* qbuf  = (float*)ws;                                    // 2 MB
    ws += (size_t)BB * NH * OUTD * sizeof(float);
    float* gat   = (float*)ws;                                    // 2 MB

    prep_kernel<<<NSUPP / 16 + BB / 4, 256, 0, stream>>>(
        user_embedding, supp_users, wk, Ksupp,
        item_embedding, history, history_len, wq, qbuf);
    attn_kernel<<<NH * BB / GB, 512, 0, stream>>>(Ksupp, qbuf, sample_index, wv, gat);
    epilogue_kernel<<<BB / 4, 256, 0, stream>>>(
        gat, item_embedding, w_out, l1_w, l1_b, l2_w, l2_b, l3_w, l3_b,
        user_bias, item_bias, x, out);
}

// Round 5
// 242.993 us; speedup vs baseline: 1.1565x; 1.1565x over previous
//
#include <hip/hip_runtime.h>
#include <math.h>

#define N_USERS 1000000
#define N_ITEMS 100000
#define EMB 16
#define OUTD 16
#define NH 4
#define HID 32
#define BB 8192
#define SS 200
#define LL 50
#define NSUPP 50000

#define SLICE_ROWS 1536
#define NP 33                               // ceil(50000/1536)
#define TBL_ROWS (NP * SLICE_ROWS)          // 50688 (padded)
#define SLICE_BYTES (SLICE_ROWS * EMB * 2)  // 49152
#define GBB 32                              // b's per attn block

typedef float v4f __attribute__((ext_vector_type(4)));
typedef _Float16 h2 __attribute__((ext_vector_type(2)));
typedef _Float16 h8 __attribute__((ext_vector_type(8)));

// within-wave DS ordering fence (lockstep wave + drain LDS ops; rule: follow
// inline-asm lgkmcnt with a sched_barrier so the compiler can't hoist past it)
#define WAVE_SYNC() do { asm volatile("s_waitcnt lgkmcnt(0)" ::: "memory"); \
                         __builtin_amdgcn_sched_barrier(0); } while (0)

// ---------------------------------------------------------------------------
// Kernel 1 (prep):
//  blocks [0, 3125):        fp16 user table: tbl[n] = (fp16) user_emb[supp[n]]
//  blocks [3125, 3125+2048): user_init -> q -> q~ (q~_e = sum_o wk[h][e][o] q_o)
//  block  3125+2048:         Wkv[h] = wk[h] @ wv[h]  (16x16 per head, fp32)
// Algebra: score = u . q~ ; ctx = (sum_s w u) @ wk ; gat = (cu @ Wkv)/l.
// K is never materialized; the gathered table is 1.6 MB total for all heads.
// ---------------------------------------------------------------------------
__global__ __launch_bounds__(256) void prep_kernel(
    const float* __restrict__ user_emb,
    const int*   __restrict__ supp_users,
    const float* __restrict__ wk,
    const float* __restrict__ wq,
    const float* __restrict__ wv,
    const float* __restrict__ item_emb,
    const int*   __restrict__ history,
    const int*   __restrict__ history_len,
    _Float16*    __restrict__ tbl,
    _Float16*    __restrict__ qtbuf,
    float*       __restrict__ Wkv)
{
    __shared__ float s_ui[4][EMB];
    __shared__ float s_wq[NH * EMB * OUTD];
    __shared__ float s_wk[NH * EMB * OUTD];
    __shared__ float s_q[4][NH * OUTD];

    int t = threadIdx.x;
    if (blockIdx.x < NSUPP / 16) {
        // ---- fp16 user table (16 rows / block) ----
        int n0 = blockIdx.x * 16;
        int ul = t >> 4, e = t & 15;
        int row = supp_users[n0 + ul];
        tbl[(size_t)(n0 + ul) * EMB + e] =
            (_Float16)user_emb[(size_t)row * EMB + e];
    } else if (blockIdx.x < NSUPP / 16 + BB / 4) {
        // ---- user_init -> q -> q~ ----
        for (int i = t; i < NH * EMB * OUTD; i += 256) {
            s_wq[i] = wq[i];
            s_wk[i] = wk[i];
        }
        int g    = t >> 6;
        int lane = t & 63;
        int l4   = lane >> 4;
        int e    = lane & 15;
        int b    = (blockIdx.x - NSUPP / 16) * 4 + g;

        float sum = 0.f;
        for (int l = l4; l < LL; l += 4) {
            int it = __builtin_nontemporal_load(history + (size_t)b * LL + l);
            sum += item_emb[(size_t)it * EMB + e];
        }
        sum += __shfl_xor(sum, 16);
        sum += __shfl_xor(sum, 32);
        if (lane < EMB) s_ui[g][lane] = sum / (float)history_len[b];
        __syncthreads();

        int h = (t >> 4) & 3;
        int o = t & 15;
        float acc = 0.f;
#pragma unroll
        for (int ee = 0; ee < EMB; ++ee)
            acc += s_ui[g][ee] * s_wq[(h * EMB + ee) * OUTD + o];
        s_q[g][h * OUTD + o] = acc;
        __syncthreads();

        // q~_e = sum_o wk[h][e][o] * q_o   (thread reuses (g,h,o->e) mapping)
        float qt = 0.f;
#pragma unroll
        for (int oo = 0; oo < OUTD; ++oo)
            qt += s_wk[(h * EMB + o) * OUTD + oo] * s_q[g][h * OUTD + oo];
        qtbuf[((size_t)b * NH + h) * EMB + o] = (_Float16)qt;
    } else {
        // ---- Wkv[h][e][p] = sum_o wk[h][e][o] * wv[h][o][p] ----
        for (int i = t; i < NH * EMB * OUTD; i += 256) {
            int h = i >> 8, e = (i >> 4) & 15, p = i & 15;
            float a = 0.f;
#pragma unroll
            for (int o = 0; o < OUTD; ++o)
                a += wk[(h * EMB + e) * OUTD + o] * wv[(h * OUTD + o) * OUTD + p];
            Wkv[i] = a;
        }
    }
}

// ---------------------------------------------------------------------------
// Kernel 2: LDS-streamed attention, grid = 256 blocks (1 per CU).
// Block = 32 b x 4 heads = 128 (h,b); 8 waves x 16 quads; quad owns one (h,b).
// Phase 0: each wave COUNTING-BUCKETS its 16 sample lists by 1536-row slice
// (hist -> serial prefix -> scatter; wave-private LDS, no block barriers).
// Main: 33 slices of the 1.6 MB fp16 user table, double-buffered 48 KB,
// reg-staged one phase ahead; quads consume their bucket from LDS.
// Per-sample: 1 ds_u16 + 2 ds_b128 + 8 fdot2 + expf + 16 fma; state (l, cu[16])
// stays in lane registers, quad-reduced at the end into gat = (cu@Wkv)/l.
// Rounds 0-3: random-L2-gather floor = 4.1 cy/row/CU (44 us). This replaces
// 6.55M random L2 requests with coalesced slice streams + LDS reads.
// ---------------------------------------------------------------------------
__global__ __launch_bounds__(512, 2) void attn_kernel(
    const _Float16* __restrict__ tbl,
    const _Float16* __restrict__ qtbuf,
    const int*   __restrict__ sample_index,
    const float* __restrict__ Wkv,
    float*       __restrict__ gat)
{
    __shared__ __align__(16) _Float16 s_slice[2][SLICE_ROWS * EMB]; // 96 KB
    __shared__ unsigned short s_list[128 * SS];                     // 51.2 KB
    __shared__ unsigned char  s_cnt[128][36];                       // 4.6 KB
    __shared__ unsigned int   s_hist[8][40];                        // 1.3 KB

    int tid  = threadIdx.x;
    int wave = tid >> 6;
    int lane = tid & 63;
    int g    = lane >> 2;
    int qt   = lane & 3;
    int hb   = wave * 16 + g;          // this quad's (h,b): 0..127
    int h    = hb & 3;
    int bl   = hb >> 2;
    int bfull = blockIdx.x * GBB + bl;

    // ---- issue slice-0 loads (in flight during bucketing) ----
    v4f stg[6];
#pragma unroll
    for (int i = 0; i < 6; ++i)
        stg[i] = *(const v4f*)((const char*)tbl + (size_t)i * 8192 + (size_t)tid * 16);

    // ---- phase 0: per-wave counting-bucket of its 16 lists ----
    for (int bs = 0; bs < 16; ++bs) {
        int hbs = wave * 16 + bs;
        int hs = hbs & 3, bls = hbs >> 2;
        const int* si = sample_index + ((size_t)hs * BB + (blockIdx.x * GBB + bls)) * SS;
        int v0 = __builtin_nontemporal_load(si + lane);
        int v1 = __builtin_nontemporal_load(si + lane + 64);
        int v2 = __builtin_nontemporal_load(si + lane + 128);
        int v3 = (lane < SS - 192) ? __builtin_nontemporal_load(si + lane + 192) : -1;

        if (lane < NP + 1) s_hist[wave][lane] = 0;
        WAVE_SYNC();
        // bucket id: v/1536 = (v>>9)/3, /3 via *21846>>16 (exact for n<=98301)
        int b0 = ((v0 >> 9) * 21846) >> 16;
        int b1 = ((v1 >> 9) * 21846) >> 16;
        int b2 = ((v2 >> 9) * 21846) >> 16;
        int b3 = (v3 >= 0) ? (((v3 >> 9) * 21846) >> 16) : 0;
        atomicAdd(&s_hist[wave][b0], 1u);
        atomicAdd(&s_hist[wave][b1], 1u);
        atomicAdd(&s_hist[wave][b2], 1u);
        if (v3 >= 0) atomicAdd(&s_hist[wave][b3], 1u);
        WAVE_SYNC();
        if (lane == 0) {
            unsigned run = 0;
            for (int k = 0; k < NP; ++k) {
                unsigned c = s_hist[wave][k];
                s_cnt[hbs][k] = (unsigned char)c;
                s_hist[wave][k] = run;
                run += c;
            }
        }
        WAVE_SYNC();
        unsigned p0 = atomicAdd(&s_hist[wave][b0], 1u);
        s_list[hbs * SS + p0] = (unsigned short)v0;
        unsigned p1 = atomicAdd(&s_hist[wave][b1], 1u);
        s_list[hbs * SS + p1] = (unsigned short)v1;
        unsigned p2 = atomicAdd(&s_hist[wave][b2], 1u);
        s_list[hbs * SS + p2] = (unsigned short)v2;
        if (v3 >= 0) {
            unsigned p3 = atomicAdd(&s_hist[wave][b3], 1u);
            s_list[hbs * SS + p3] = (unsigned short)v3;
        }
        WAVE_SYNC();
    }

    // ---- q~ for this quad (16 fp16 = 2 x h8, all 4 lanes hold a copy) ----
    const h8* qtp = (const h8*)(qtbuf + ((size_t)bfull * NH + h) * EMB);
    h8 qA = qtp[0], qB = qtp[1];
    h2 tq0 = __builtin_shufflevector(qA, qA, 0, 1);
    h2 tq1 = __builtin_shufflevector(qA, qA, 2, 3);
    h2 tq2 = __builtin_shufflevector(qA, qA, 4, 5);
    h2 tq3 = __builtin_shufflevector(qA, qA, 6, 7);
    h2 tq4 = __builtin_shufflevector(qB, qB, 0, 1);
    h2 tq5 = __builtin_shufflevector(qB, qB, 2, 3);
    h2 tq6 = __builtin_shufflevector(qB, qB, 4, 5);
    h2 tq7 = __builtin_shufflevector(qB, qB, 6, 7);

    // publish slice 0
#pragma unroll
    for (int i = 0; i < 6; ++i)
        *(v4f*)((char*)&s_slice[0][0] + (size_t)i * 8192 + (size_t)tid * 16) = stg[i];
    __syncthreads();

    // ---- main loop over 33 slices ----
    float l = 0.f;
    float cu[16];
#pragma unroll
    for (int j = 0; j < 16; ++j) cu[j] = 0.f;
    int base = 0;

    for (int p = 0; p < NP; ++p) {
        if (p + 1 < NP) {                      // issue next slice (reg-staged)
            size_t sb = (size_t)(p + 1) * SLICE_BYTES;
#pragma unroll
            for (int i = 0; i < 6; ++i)
                stg[i] = *(const v4f*)((const char*)tbl + sb + (size_t)i * 8192
                                        + (size_t)tid * 16);
        }
        const h8* sl = (const h8*)&s_slice[p & 1][0];
        int cnt = (int)s_cnt[hb][p];
        int pbase = p * SLICE_ROWS;

        for (int it = 0;; ++it) {
            int off = it * 4 + qt;
            bool valid = off < cnt;
            if (__ballot(valid) == 0ull) break;
            int pos = valid ? base + off : 0;
            int v   = (int)s_list[hb * SS + pos];
            int rl  = valid ? v - pbase : 0;
            h8 u0 = sl[rl * 2];
            h8 u1 = sl[rl * 2 + 1];
            h2 a0 = __builtin_shufflevector(u0, u0, 0, 1);
            h2 a1 = __builtin_shufflevector(u0, u0, 2, 3);
            h2 a2 = __builtin_shufflevector(u0, u0, 4, 5);
            h2 a3 = __builtin_shufflevector(u0, u0, 6, 7);
            h2 a4 = __builtin_shufflevector(u1, u1, 0, 1);
            h2 a5 = __builtin_shufflevector(u1, u1, 2, 3);
            h2 a6 = __builtin_shufflevector(u1, u1, 4, 5);
            h2 a7 = __builtin_shufflevector(u1, u1, 6, 7);
            float s = __builtin_amdgcn_fdot2(a0, tq0,
                      __builtin_amdgcn_fdot2(a1, tq1,
                      __builtin_amdgcn_fdot2(a2, tq2,
                      __builtin_amdgcn_fdot2(a3, tq3,
                      __builtin_amdgcn_fdot2(a4, tq4,
                      __builtin_amdgcn_fdot2(a5, tq5,
                      __builtin_amdgcn_fdot2(a6, tq6,
                      __builtin_amdgcn_fdot2(a7, tq7,
                      0.f, false), false), false), false),
                      false), false), false), false);
            float w = valid ? __expf(s) : 0.f;   // no-max softmax (|s|~1e-5)
            l += w;
#pragma unroll
            for (int j = 0; j < 8; ++j) cu[j]     += w * (float)u0[j];
#pragma unroll
            for (int j = 0; j < 8; ++j) cu[8 + j] += w * (float)u1[j];
        }
        base += cnt;
        __syncthreads();                        // all reads of s_slice[p&1] done
        if (p + 1 < NP) {
#pragma unroll
            for (int i = 0; i < 6; ++i)
                *(v4f*)((char*)&s_slice[(p + 1) & 1][0] + (size_t)i * 8192
                        + (size_t)tid * 16) = stg[i];
        }
        __syncthreads();                        // next slice visible
    }

    // ---- quad reduce + gat = (cu @ Wkv[h]) / l ----
    l += __shfl_xor(l, 1);
    l += __shfl_xor(l, 2);
#pragma unroll
    for (int j = 0; j < 16; ++j) {
        cu[j] += __shfl_xor(cu[j], 1);
        cu[j] += __shfl_xor(cu[j], 2);
    }
    float inv = 1.f / l;
    v4f acc = {0.f, 0.f, 0.f, 0.f};
#pragma unroll
    for (int e = 0; e < EMB; ++e)
        acc += cu[e] * *(const v4f*)(Wkv + ((size_t)(h * EMB + e) * OUTD) + qt * 4);
    acc *= inv;
    *(v4f*)(gat + (size_t)bfull * (NH * OUTD) + h * OUTD + qt * 4) = acc;
}

// ---------------------------------------------------------------------------
// Kernel 3: epilogue per b (4 b per 256-thread block, one wave per b).
// ---------------------------------------------------------------------------
__global__ __launch_bounds__(256) void epilogue_kernel(
    const float* __restrict__ gat,
    const float* __restrict__ item_emb,
    const float* __restrict__ w_out,
    const float* __restrict__ l1_w, const float* __restrict__ l1_b,
    const float* __restrict__ l2_w, const float* __restrict__ l2_b,
    const float* __restrict__ l3_w, const float* __restrict__ l3_b,
    const float* __restrict__ user_bias, const float* __restrict__ item_bias,
    const int*   __restrict__ x,
    float*       __restrict__ out)
{
    int t    = threadIdx.x;
    int g    = t >> 6;
    int lane = t & 63;
    int b    = blockIdx.x * 4 + g;

    __shared__ float s_gat[4][NH * OUTD];
    __shared__ float s_ue[4][OUTD];
    __shared__ float s_ie[4][EMB];
    __shared__ float s_x1[4][HID];
    __shared__ float s_x2[4][HID / 2];

    int uid = x[(size_t)b * 2 + 0];
    int iid = x[(size_t)b * 2 + 1];

    s_gat[g][lane] = gat[(size_t)b * (NH * OUTD) + lane];
    if (lane < EMB) s_ie[g][lane] = item_emb[(size_t)iid * EMB + lane];
    __syncthreads();

    if (lane < OUTD) {
        float acc = 0.f;
#pragma unroll
        for (int j = 0; j < NH * OUTD; ++j) acc += s_gat[g][j] * w_out[j * OUTD + lane];
        s_ue[g][lane] = acc;
    }
    __syncthreads();

    if (lane < HID) {
        float acc = l1_b[lane];
#pragma unroll
        for (int i = 0; i < EMB; ++i) {
            float ue = s_ue[g][i], ie = s_ie[g][i];
            acc += ue * l1_w[i * HID + lane]
                 + ie * l1_w[(EMB + i) * HID + lane]
                 + ue * ie * l1_w[(2 * EMB + i) * HID + lane];
        }
        s_x1[g][lane] = tanhf(acc);
    }
    __syncthreads();

    if (lane < HID / 2) {
        float acc = l2_b[lane];
#pragma unroll
        for (int j = 0; j < HID; ++j) acc += s_x1[g][j] * l2_w[j * (HID / 2) + lane];
        s_x2[g][lane] = tanhf(acc);
    }
    __syncthreads();

    if (lane == 0) {
        float x3 = l3_b[0];
#pragma unroll
        for (int j = 0; j < HID / 2; ++j) x3 += s_x2[g][j] * l3_w[j];
        float ratings = 0.f;
#pragma unroll
        for (int o = 0; o < OUTD; ++o) ratings += s_ue[g][o] * s_ie[g][o];
        out[b] = 0.5f * (ratings + x3) + user_bias[uid] + item_bias[iid];
    }
}

// ---------------------------------------------------------------------------
extern "C" void kernel_launch(void* const* d_in, const int* in_sizes, int n_in,
                              void* d_out, int out_size, void* d_ws, size_t ws_size,
                              hipStream_t stream) {
    const float* user_embedding = (const float*)d_in[0];
    const float* item_embedding = (const float*)d_in[1];
    const float* wq             = (const float*)d_in[2];
    const float* wk             = (const float*)d_in[3];
    const float* wv             = (const float*)d_in[4];
    const float* w_out          = (const float*)d_in[5];
    const float* l1_w           = (const float*)d_in[6];
    const float* l1_b           = (const float*)d_in[7];
    const float* l2_w           = (const float*)d_in[8];
    const float* l2_b           = (const float*)d_in[9];
    const float* l3_w           = (const float*)d_in[10];
    const float* l3_b           = (const float*)d_in[11];
    const float* user_bias      = (const float*)d_in[12];
    const float* item_bias      = (const float*)d_in[13];
    const int*   x              = (const int*)d_in[14];
    const int*   history        = (const int*)d_in[15];
    const int*   history_len    = (const int*)d_in[16];
    const int*   supp_users     = (const int*)d_in[17];
    const int*   sample_index   = (const int*)d_in[18];
    float* out = (float*)d_out;

    char* ws = (char*)d_ws;
    _Float16* tbl = (_Float16*)ws;                       // 50688*32 B = 1.62 MB
    ws += (size_t)TBL_ROWS * EMB * sizeof(_Float16);
    _Float16* qtbuf = (_Float16*)ws;                     // 1 MB
    ws += (size_t)BB * NH * EMB * sizeof(_Float16);
    float* gat = (float*)ws;                             // 2 MB
    ws += (size_t)BB * NH * OUTD * sizeof(float);
    float* Wkv = (float*)ws;                             // 4 KB

    prep_kernel<<<NSUPP / 16 + BB / 4 + 1, 256, 0, stream>>>(
        user_embedding, supp_users, wk, wq, wv,
        item_embedding, history, history_len, tbl, qtbuf, Wkv);
    attn_kernel<<<BB / GBB, 512, 0, stream>>>(tbl, qtbuf, sample_index, Wkv, gat);
    epilogue_kernel<<<BB / 4, 256, 0, stream>>>(
        gat, item_embedding, w_out, l1_w, l1_b, l2_w, l2_b, l3_w, l3_b,
        user_bias, item_bias, x, out);
}